// Round 1
// baseline (744.694 us; speedup 1.0000x reference)
//
#include <hip/hip_runtime.h>

#define WH 9216
#define NF 64
#define NC 32
#define NH 8
#define IMGW 96
#define IMGH 96

// ---------------- kernel 1: Qs (head-summed Q) and K, in (WH, F) row-major ----------------
__global__ __launch_bounds__(256) void qsk_kernel(
    const float* __restrict__ X, const float* __restrict__ WQ_task,
    const float* __restrict__ BQ_task, const float* __restrict__ WK_task,
    const float* __restrict__ BK_task, const float* __restrict__ WQ_t1,
    const float* __restrict__ WQ_x, const float* __restrict__ BQ,
    const float* __restrict__ WK_x, const float* __restrict__ BK,
    const float* __restrict__ prevQ,
    float* __restrict__ qs, float* __restrict__ kmat)
{
  __shared__ float Qt[64][65];
  __shared__ float Kt[64][65];
  const int wh0 = blockIdx.x * 64;
  const int t = threadIdx.x;
  // compute phase: lanes sweep wh (coalesced global reads), f wave-uniform
  #pragma unroll
  for (int i = 0; i < 16; ++i) {
    const int f = i * 4 + (t >> 6);
    const int whl = t & 63;
    const int wh = wh0 + whl;
    const float x = X[(size_t)f * WH + wh];
    const float kv = WK_task[f] * fmaxf(fmaf(WK_x[f], x, BK[f]), 0.f) + BK_task[f];
    Kt[whl][f] = kv;
    const float xq = WQ_x[f] * x;
    float qsum = 0.f;
    #pragma unroll
    for (int a = 0; a < NH; ++a) {
      const int af = a * 64 + f;
      const float pq = prevQ[(size_t)af * WH + wh];
      const float r = fmaxf(WQ_t1[af] * pq + xq + BQ[af], 0.f);
      qsum += fmaf(WQ_task[af], r, BQ_task[af]);
    }
    Qt[whl][f] = qsum;
  }
  __syncthreads();
  // write phase: lanes sweep f (coalesced global writes)
  #pragma unroll
  for (int i = 0; i < 16; ++i) {
    const int o = i * 256 + t;
    const int whl = o >> 6, f = o & 63;
    qs[(size_t)(wh0 + whl) * 64 + f] = Qt[whl][f];
    kmat[(size_t)(wh0 + whl) * 64 + f] = Kt[whl][f];
  }
}

// ---------------- kernel 2: V = WV_task * (conv3x3(X) + b) + BV_task, layout (C, WH) ----------------
__global__ __launch_bounds__(256) void vconv_kernel(
    const float* __restrict__ X, const float* __restrict__ Wc,
    const float* __restrict__ bc, const float* __restrict__ WV_task,
    const float* __restrict__ BV_task, float* __restrict__ vmat)
{
  const int c = blockIdx.y;
  const int wh = blockIdx.x * 256 + threadIdx.x;
  const int w = wh / IMGH;
  const int h = wh - w * IMGH;
  float acc = bc[c];
  for (int f = 0; f < NF; ++f) {
    const float* xf = X + (size_t)f * WH;
    const float* wf = Wc + ((size_t)c * NF + f) * 9;
    #pragma unroll
    for (int di = 0; di < 3; ++di) {
      const int ww = w + di - 1;
      if (ww < 0 || ww >= IMGW) continue;
      #pragma unroll
      for (int dj = 0; dj < 3; ++dj) {
        const int hh = h + dj - 1;
        if (hh < 0 || hh >= IMGH) continue;
        acc = fmaf(xf[ww * IMGH + hh], wf[di * 3 + dj], acc);
      }
    }
  }
  vmat[(size_t)c * WH + wh] = fmaf(WV_task[c], acc, BV_task[c]);
}

// ---------------- kernel 3: key-split flash attention, fp32, partials (m,l,acc[32]) ----------------
__global__ __launch_bounds__(256) void flash_partial(
    const float* __restrict__ qs, const float* __restrict__ kmat,
    const float* __restrict__ vmat, float* __restrict__ part, int kps)
{
  __shared__ __align__(16) float Kl[64 * 64];   // [k][f]
  __shared__ __align__(16) float Vl[64 * 36];   // [k][c], padded row stride 36
  const int t = threadIdx.x;
  const int q = blockIdx.x * 256 + t;
  const int s = blockIdx.y;
  const int kbeg = s * kps;

  float4 qr[16];
  {
    const float4* qrow = (const float4*)(qs + (size_t)q * 64);
    #pragma unroll
    for (int i = 0; i < 16; ++i) qr[i] = qrow[i];
  }
  float m = -1e30f, l = 0.f;
  float4 acc[8];
  #pragma unroll
  for (int i = 0; i < 8; ++i) acc[i] = make_float4(0.f, 0.f, 0.f, 0.f);

  for (int kc = kbeg; kc < kbeg + kps; kc += 64) {
    __syncthreads();
    // stage K chunk: 64 keys x 64 feats (contiguous, coalesced)
    {
      const float4* src = (const float4*)(kmat + (size_t)kc * 64);
      float4* dst = (float4*)Kl;
      #pragma unroll
      for (int i = 0; i < 4; ++i) dst[i * 256 + t] = src[i * 256 + t];
    }
    // stage V chunk: transpose (C,WH) -> [k][c]
    #pragma unroll
    for (int i = 0; i < 8; ++i) {
      const int idx = i * 256 + t;     // 0..2047
      const int c = idx >> 6;          // wave-uniform
      const int k = idx & 63;          // lane -> coalesced read
      Vl[k * 36 + c] = vmat[(size_t)c * WH + kc + k];
    }
    __syncthreads();

    #pragma unroll 2
    for (int k = 0; k < 64; ++k) {
      const float4* krow = (const float4*)(Kl + k * 64);
      float s0 = 0.f, s1 = 0.f, s2 = 0.f, s3 = 0.f;
      #pragma unroll
      for (int i = 0; i < 16; ++i) {
        const float4 kv = krow[i];      // broadcast read, conflict-free
        s0 = fmaf(qr[i].x, kv.x, s0);
        s1 = fmaf(qr[i].y, kv.y, s1);
        s2 = fmaf(qr[i].z, kv.z, s2);
        s3 = fmaf(qr[i].w, kv.w, s3);
      }
      const float sim = (s0 + s1) + (s2 + s3);
      const float4* vrow = (const float4*)(Vl + k * 36);
      if (__any(sim > m)) {
        // wave-uniform heavy path: rescale accumulators
        const float nm = fmaxf(m, sim);
        const float r = __expf(m - nm);
        const float p = __expf(sim - nm);
        l = l * r + p;
        #pragma unroll
        for (int i = 0; i < 8; ++i) {
          const float4 v = vrow[i];
          acc[i].x = fmaf(acc[i].x, r, p * v.x);
          acc[i].y = fmaf(acc[i].y, r, p * v.y);
          acc[i].z = fmaf(acc[i].z, r, p * v.z);
          acc[i].w = fmaf(acc[i].w, r, p * v.w);
        }
        m = nm;
      } else {
        const float p = __expf(sim - m);
        l += p;
        #pragma unroll
        for (int i = 0; i < 8; ++i) {
          const float4 v = vrow[i];
          acc[i].x = fmaf(p, v.x, acc[i].x);
          acc[i].y = fmaf(p, v.y, acc[i].y);
          acc[i].z = fmaf(p, v.z, acc[i].z);
          acc[i].w = fmaf(p, v.w, acc[i].w);
        }
      }
    }
  }
  float* rec = part + ((size_t)s * WH + q) * 34;
  rec[0] = m;
  rec[1] = l;
  #pragma unroll
  for (int i = 0; i < 8; ++i) {
    rec[2 + 4 * i + 0] = acc[i].x;
    rec[2 + 4 * i + 1] = acc[i].y;
    rec[2 + 4 * i + 2] = acc[i].z;
    rec[2 + 4 * i + 3] = acc[i].w;
  }
}

// ---------------- kernel 4: merge key-splits -> out (C, W, H) ----------------
__global__ __launch_bounds__(256) void merge_kernel(
    const float* __restrict__ part, float* __restrict__ out, int ksplit)
{
  const int idx = blockIdx.x * 256 + threadIdx.x;   // c*WH + wh
  const int c = idx / WH;
  const int wh = idx - c * WH;
  float M = -1e30f;
  for (int s = 0; s < ksplit; ++s)
    M = fmaxf(M, part[((size_t)s * WH + wh) * 34]);
  float L = 0.f, A = 0.f;
  for (int s = 0; s < ksplit; ++s) {
    const float* rec = part + ((size_t)s * WH + wh) * 34;
    const float e = __expf(rec[0] - M);
    L = fmaf(e, rec[1], L);
    A = fmaf(e, rec[2 + c], A);
  }
  out[idx] = A / L;
}

extern "C" void kernel_launch(void* const* d_in, const int* in_sizes, int n_in,
                              void* d_out, int out_size, void* d_ws, size_t ws_size,
                              hipStream_t stream)
{
  const float* X   = (const float*)d_in[0];
  const float* WQt = (const float*)d_in[1];
  const float* BQt = (const float*)d_in[2];
  const float* WKt = (const float*)d_in[3];
  const float* BKt = (const float*)d_in[4];
  const float* WVt = (const float*)d_in[5];
  const float* BVt = (const float*)d_in[6];
  const float* WQ1 = (const float*)d_in[7];
  const float* WQx = (const float*)d_in[8];
  const float* BQ  = (const float*)d_in[9];
  const float* WKx = (const float*)d_in[10];
  const float* BK  = (const float*)d_in[11];
  const float* Wc  = (const float*)d_in[12];
  const float* bc  = (const float*)d_in[13];
  const float* pQ  = (const float*)d_in[14];
  float* out = (float*)d_out;

  float* qs   = (float*)d_ws;                 // (WH, 64)
  float* kmat = qs + (size_t)WH * 64;         // (WH, 64)
  float* vmat = kmat + (size_t)WH * 64;       // (C, WH)
  float* part = vmat + (size_t)WH * 32;       // [ksplit][WH][34]
  const size_t base_bytes = (size_t)WH * (64 + 64 + 32) * sizeof(float);

  int ksplit = 16;   // must divide 144 chunks: 16,8,4,2,1 all OK
  while (ksplit > 1 && base_bytes + (size_t)ksplit * WH * 34 * sizeof(float) > ws_size)
    ksplit >>= 1;
  const int kps = WH / ksplit;

  qsk_kernel<<<dim3(WH / 64), 256, 0, stream>>>(X, WQt, BQt, WKt, BKt,
                                                WQ1, WQx, BQ, WKx, BK, pQ, qs, kmat);
  vconv_kernel<<<dim3(WH / 256, NC), 256, 0, stream>>>(X, Wc, bc, WVt, BVt, vmat);
  flash_partial<<<dim3(WH / 256, ksplit), 256, 0, stream>>>(qs, kmat, vmat, part, kps);
  merge_kernel<<<dim3((NC * WH) / 256), 256, 0, stream>>>(part, out, ksplit);
}

// Round 2
// 196.629 us; speedup vs baseline: 3.7873x; 3.7873x over previous
//
#include <hip/hip_runtime.h>

#define WH 9216
#define NF 64
#define NC 32
#define NH 8
#define IMGW 96
#define IMGH 96

typedef float f32x4 __attribute__((ext_vector_type(4)));
typedef short short8 __attribute__((ext_vector_type(8)));

__device__ inline short bf16_bits(float x) {
  __bf16 h = (__bf16)x;
  return __builtin_bit_cast(short, h);
}

// ---------------- kernel 1: Qs (head-summed Q) and K -> bf16 hi/lo frag-ready layouts ----
// qfrag/kfrag records: [tile 576][term 4][lane 64] of short8 (8 bf16).
// term 0: hi f0-31, 1: hi f32-63, 2: lo f0-31, 3: lo f32-63.
// element (lane,e) = M[tile*16 + (lane&15)][fb + 8*(lane>>4) + e]   (A/B frag layout)
__global__ __launch_bounds__(256) void qsk_kernel(
    const float* __restrict__ X, const float* __restrict__ WQ_task,
    const float* __restrict__ BQ_task, const float* __restrict__ WK_task,
    const float* __restrict__ BK_task, const float* __restrict__ WQ_t1,
    const float* __restrict__ WQ_x, const float* __restrict__ BQ,
    const float* __restrict__ WK_x, const float* __restrict__ BK,
    const float* __restrict__ prevQ,
    short8* __restrict__ qfrag, short8* __restrict__ kfrag)
{
  __shared__ float Qt[64][65];
  __shared__ float Kt[64][65];
  const int t = threadIdx.x;
  const int wh0 = blockIdx.x * 64;
  // compute phase: lanes sweep wh (coalesced), f wave-uniform
  #pragma unroll
  for (int i = 0; i < 16; ++i) {
    const int f = i * 4 + (t >> 6);
    const int whl = t & 63;
    const int wh = wh0 + whl;
    const float x = X[(size_t)f * WH + wh];
    Kt[whl][f] = WK_task[f] * fmaxf(fmaf(WK_x[f], x, BK[f]), 0.f) + BK_task[f];
    const float xq = WQ_x[f] * x;
    float qsum = 0.f;
    #pragma unroll
    for (int a = 0; a < NH; ++a) {
      const int af = a * 64 + f;
      const float pq = prevQ[(size_t)af * WH + wh];
      const float r = fmaxf(WQ_t1[af] * pq + xq + BQ[af], 0.f);
      qsum += fmaf(WQ_task[af], r, BQ_task[af]);
    }
    Qt[whl][f] = qsum;
  }
  __syncthreads();
  // frag write phase
  const int lane = t & 63;
  const int tileL = t >> 6;
  const int row = tileL * 16 + (lane & 15);
  const int f0 = 8 * (lane >> 4);
  const int T = blockIdx.x * 4 + tileL;
  #pragma unroll
  for (int term = 0; term < 4; ++term) {
    const int fb = (term & 1) * 32;
    short8 fq, fk;
    #pragma unroll
    for (int e = 0; e < 8; ++e) {
      const float xq = Qt[row][fb + f0 + e];
      const float xk = Kt[row][fb + f0 + e];
      if (term < 2) {
        fq[e] = bf16_bits(xq);
        fk[e] = bf16_bits(xk);
      } else {
        const float hq = (float)(__bf16)xq;
        const float hk = (float)(__bf16)xk;
        fq[e] = bf16_bits(xq - hq);
        fk[e] = bf16_bits(xk - hk);
      }
    }
    qfrag[((size_t)T * 4 + term) * 64 + lane] = fq;
    kfrag[((size_t)T * 4 + term) * 64 + lane] = fk;
  }
}

// ---------------- kernel 2: V conv -> bf16 frag-ready A-layout with baked key-permutation ----
// vfrag[ch 288][ct 2][lane 64] short8; element (lane,e) =
//   V[ch*32 + 16*(e>>2) + 4*(lane>>4) + (e&3)][ct*16 + (lane&15)]
__global__ __launch_bounds__(256) void vconv_kernel(
    const float* __restrict__ X, const float* __restrict__ Wc,
    const float* __restrict__ bc, const float* __restrict__ WV_task,
    const float* __restrict__ BV_task, short* __restrict__ vfrag)
{
  const int ch = blockIdx.x;
  const int t = threadIdx.x;
  const int lane = t & 63, quad = t >> 6;
  const int ct = quad >> 1, eh = quad & 1;          // eh = e>>2 half
  const int c = ct * 16 + (lane & 15);
  const int wh0 = ch * 32 + eh * 16 + 4 * (lane >> 4);
  const int w = wh0 / IMGH, h0 = wh0 - w * IMGH;    // 4 consecutive h, no row wrap
  float a0 = bc[c], a1 = a0, a2 = a0, a3 = a0;
  for (int f = 0; f < NF; ++f) {
    const float* xf = X + (size_t)f * WH;
    const float* wf = Wc + ((size_t)c * NF + f) * 9;
    #pragma unroll
    for (int di = 0; di < 3; ++di) {
      const int ww = w + di - 1;
      if (ww < 0 || ww >= IMGW) continue;
      float x6[6];
      #pragma unroll
      for (int j = 0; j < 6; ++j) {
        const int hh = h0 + j - 1;
        x6[j] = (hh >= 0 && hh < IMGH) ? xf[ww * IMGH + hh] : 0.f;
      }
      const float w0 = wf[di * 3 + 0], w1 = wf[di * 3 + 1], w2 = wf[di * 3 + 2];
      a0 = fmaf(x6[0], w0, fmaf(x6[1], w1, fmaf(x6[2], w2, a0)));
      a1 = fmaf(x6[1], w0, fmaf(x6[2], w1, fmaf(x6[3], w2, a1)));
      a2 = fmaf(x6[2], w0, fmaf(x6[3], w1, fmaf(x6[4], w2, a2)));
      a3 = fmaf(x6[3], w0, fmaf(x6[4], w1, fmaf(x6[5], w2, a3)));
    }
  }
  const float wv = WV_task[c], bv = BV_task[c];
  short4 vv;
  vv.x = bf16_bits(fmaf(wv, a0, bv));
  vv.y = bf16_bits(fmaf(wv, a1, bv));
  vv.z = bf16_bits(fmaf(wv, a2, bv));
  vv.w = bf16_bits(fmaf(wv, a3, bv));
  // position: ((ch*2+ct)*64 + lane)*8 + eh*4 shorts
  ((short4*)vfrag)[(((size_t)ch * 2 + ct) * 64 + lane) * 2 + eh] = vv;
}

// ---------------- kernel 3: MFMA flash attention ----------------
// block = 4 waves; all waves share 48 queries (3 col-groups of 16);
// waves stride over 32-key chunks within the block's key-split range.
__global__ __launch_bounds__(256, 3) void flash_mfma(
    const short8* __restrict__ qfrag, const short8* __restrict__ kfrag,
    const short8* __restrict__ vfrag, float* __restrict__ part, int cps)
{
  const int t = threadIdx.x;
  const int lane = t & 63, wave = t >> 6;
  const int h = lane >> 4;
  const int qb = blockIdx.x;      // 0..191
  const int s = blockIdx.y;       // key split

  // persistent Q fragments: 3 groups x 4 terms
  short8 qf[3][4];
  #pragma unroll
  for (int g = 0; g < 3; ++g)
    #pragma unroll
    for (int tm = 0; tm < 4; ++tm)
      qf[g][tm] = qfrag[((size_t)(qb * 3 + g) * 4 + tm) * 64 + lane];

  f32x4 acc[2][3];
  #pragma unroll
  for (int ct = 0; ct < 2; ++ct)
    #pragma unroll
    for (int g = 0; g < 3; ++g)
      acc[ct][g] = (f32x4){0.f, 0.f, 0.f, 0.f};
  float m[3] = {-1e30f, -1e30f, -1e30f};
  float l[3] = {0.f, 0.f, 0.f};

  const int cpw = cps >> 2;        // chunks per wave
  const int ch0 = s * cps + wave;
  for (int it = 0; it < cpw; ++it) {
    const int ch = ch0 + it * 4;
    // load K fragments (2 key-tiles x 4 terms) and V fragments (2 c-tiles)
    short8 kf[2][4];
    #pragma unroll
    for (int kt = 0; kt < 2; ++kt)
      #pragma unroll
      for (int tm = 0; tm < 4; ++tm)
        kf[kt][tm] = kfrag[((size_t)(2 * ch + kt) * 4 + tm) * 64 + lane];
    short8 vf0 = vfrag[(size_t)(ch * 2 + 0) * 64 + lane];
    short8 vf1 = vfrag[(size_t)(ch * 2 + 1) * 64 + lane];

    // sim: S^T[key][q], split-precision 3-term bf16
    f32x4 st[2][3];
    #pragma unroll
    for (int kt = 0; kt < 2; ++kt)
      #pragma unroll
      for (int g = 0; g < 3; ++g) {
        f32x4 a = (f32x4){0.f, 0.f, 0.f, 0.f};
        a = __builtin_amdgcn_mfma_f32_16x16x32_bf16(kf[kt][0], qf[g][0], a, 0, 0, 0);
        a = __builtin_amdgcn_mfma_f32_16x16x32_bf16(kf[kt][1], qf[g][1], a, 0, 0, 0);
        a = __builtin_amdgcn_mfma_f32_16x16x32_bf16(kf[kt][2], qf[g][0], a, 0, 0, 0);
        a = __builtin_amdgcn_mfma_f32_16x16x32_bf16(kf[kt][3], qf[g][1], a, 0, 0, 0);
        a = __builtin_amdgcn_mfma_f32_16x16x32_bf16(kf[kt][0], qf[g][2], a, 0, 0, 0);
        a = __builtin_amdgcn_mfma_f32_16x16x32_bf16(kf[kt][1], qf[g][3], a, 0, 0, 0);
        st[kt][g] = a;
      }

    // online softmax + PV per q-group
    #pragma unroll
    for (int g = 0; g < 3; ++g) {
      float p[8];
      #pragma unroll
      for (int e = 0; e < 4; ++e) { p[e] = st[0][g][e]; p[4 + e] = st[1][g][e]; }
      float tmax = fmaxf(fmaxf(fmaxf(p[0], p[1]), fmaxf(p[2], p[3])),
                         fmaxf(fmaxf(p[4], p[5]), fmaxf(p[6], p[7])));
      tmax = fmaxf(tmax, __shfl_xor(tmax, 16));
      tmax = fmaxf(tmax, __shfl_xor(tmax, 32));
      if (__any(tmax > m[g] + 8.f)) {
        const float nm = fmaxf(m[g], tmax);
        const float r = __expf(m[g] - nm);
        l[g] *= r;
        acc[0][g] *= r;
        acc[1][g] *= r;
        m[g] = nm;
      }
      short8 pb;
      float ls = 0.f;
      #pragma unroll
      for (int e = 0; e < 8; ++e) {
        const float pe = __expf(p[e] - m[g]);
        ls += pe;
        pb[e] = bf16_bits(pe);
      }
      l[g] += ls;
      acc[0][g] = __builtin_amdgcn_mfma_f32_16x16x32_bf16(vf0, pb, acc[0][g], 0, 0, 0);
      acc[1][g] = __builtin_amdgcn_mfma_f32_16x16x32_bf16(vf1, pb, acc[1][g], 0, 0, 0);
    }
  }

  // epilogue: per-wave partial record {acc[32], m, l}
  const int u = s * 4 + wave;
  #pragma unroll
  for (int g = 0; g < 3; ++g) {
    float lf = l[g] + __shfl_xor(l[g], 16);
    lf += __shfl_xor(lf, 32);
    const int q = qb * 48 + g * 16 + (lane & 15);
    float* base = part + ((size_t)u * WH + q) * 36;
    *(f32x4*)(base + 0 + 4 * h) = acc[0][g];
    *(f32x4*)(base + 16 + 4 * h) = acc[1][g];
    if (h == 0) { base[32] = m[g]; base[33] = lf; }
  }
}

// ---------------- kernel 4: merge partials -> out (C, W, H) ----------------
__global__ __launch_bounds__(256) void merge_kernel(
    const float* __restrict__ part, float* __restrict__ out, int units)
{
  const int t = threadIdx.x;
  const int cl = t & 31;
  const int wh = blockIdx.x * 8 + (t >> 5);
  float M = -1e30f;
  for (int u = 0; u < units; ++u)
    M = fmaxf(M, part[((size_t)u * WH + wh) * 36 + 32]);
  float L = 0.f, A = 0.f;
  for (int u = 0; u < units; ++u) {
    const float* base = part + ((size_t)u * WH + wh) * 36;
    const float e = __expf(base[32] - M);
    L = fmaf(e, base[33], L);
    A = fmaf(e, base[cl], A);
  }
  out[(size_t)cl * WH + wh] = A / L;
}

extern "C" void kernel_launch(void* const* d_in, const int* in_sizes, int n_in,
                              void* d_out, int out_size, void* d_ws, size_t ws_size,
                              hipStream_t stream)
{
  const float* X   = (const float*)d_in[0];
  const float* WQt = (const float*)d_in[1];
  const float* BQt = (const float*)d_in[2];
  const float* WKt = (const float*)d_in[3];
  const float* BKt = (const float*)d_in[4];
  const float* WVt = (const float*)d_in[5];
  const float* BVt = (const float*)d_in[6];
  const float* WQ1 = (const float*)d_in[7];
  const float* WQx = (const float*)d_in[8];
  const float* BQ  = (const float*)d_in[9];
  const float* WKx = (const float*)d_in[10];
  const float* BK  = (const float*)d_in[11];
  const float* Wc  = (const float*)d_in[12];
  const float* bc  = (const float*)d_in[13];
  const float* pQ  = (const float*)d_in[14];
  float* out = (float*)d_out;

  short8* qfrag = (short8*)d_ws;                       // 576*4*64 records
  short8* kfrag = qfrag + (size_t)576 * 4 * 64;
  short8* vfrag = kfrag + (size_t)576 * 4 * 64;        // 288*2*64 records
  float*  part  = (float*)(vfrag + (size_t)288 * 2 * 64);
  const size_t base_bytes = ((size_t)576 * 4 * 64 * 2 + (size_t)288 * 2 * 64) * 16;

  int ksplit = 4;
  while (ksplit > 1 &&
         base_bytes + (size_t)(4 * ksplit) * WH * 36 * sizeof(float) > ws_size)
    ksplit >>= 1;
  const int cps = 288 / ksplit;     // key-chunks per split
  const int units = 4 * ksplit;

  qsk_kernel<<<dim3(WH / 64), 256, 0, stream>>>(X, WQt, BQt, WKt, BKt,
                                                WQ1, WQx, BQ, WKx, BK, pQ,
                                                qfrag, kfrag);
  vconv_kernel<<<dim3(288), 256, 0, stream>>>(X, Wc, bc, WVt, BVt, (short*)vfrag);
  flash_mfma<<<dim3(192, ksplit), 256, 0, stream>>>(qfrag, kfrag, vfrag, part, cps);
  merge_kernel<<<dim3(WH / 8), 256, 0, stream>>>(part, out, units);
}

// Round 3
// 87.952 us; speedup vs baseline: 8.4671x; 2.2356x over previous
//
#include <hip/hip_runtime.h>

#define WH 9216
#define NF 64
#define NC 32
#define NH 8
#define IMGW 96
#define IMGH 96
#define PW 98
#define PPLANE 9604

typedef float f32x4 __attribute__((ext_vector_type(4)));
typedef short short8 __attribute__((ext_vector_type(8)));

__device__ inline short bf16_bits(float x) {
  __bf16 h = (__bf16)x;
  return __builtin_bit_cast(short, h);
}
__device__ inline float bf16_round(float x) { return (float)(__bf16)x; }

// ---------------- kernel A: pad X to bf16 (98x98 planes, zero border) + pack weight frags ----
// wfrag[ct 2][cc 18][lane 64] short8: element (lane,e) =
//   WVt[c] * Wc[c][f][tap],  c = ct*16+(lane&15), k = cc*32 + 8*(lane>>4)+e = tap*64 + f
__global__ __launch_bounds__(256) void pad_wpack_kernel(
    const float* __restrict__ X, const float* __restrict__ Wc,
    const float* __restrict__ WV_task,
    unsigned short* __restrict__ padX, short8* __restrict__ wfrag)
{
  const int bid = blockIdx.x;
  const int t = threadIdx.x;
  if (bid < 2401) {
    const int idx = bid * 256 + t;            // f*9604 + p, 64*9604 = 614656 exactly
    const int f = idx / PPLANE;
    const int p = idx - f * PPLANE;
    const int pw = p / PW;
    const int ph = p - pw * PW;
    float v = 0.f;
    if (pw >= 1 && pw <= IMGW && ph >= 1 && ph <= IMGH)
      v = X[(size_t)f * WH + (pw - 1) * IMGH + (ph - 1)];
    padX[idx] = (unsigned short)bf16_bits(v);
  } else {
    #pragma unroll
    for (int j = 0; j < 9; ++j) {
      const int ridx = j * 256 + t;           // 2304 records
      const int ct = ridx / 1152;
      const int rem = ridx - ct * 1152;
      const int cc = rem >> 6;
      const int lane = rem & 63;
      const int c = ct * 16 + (lane & 15);
      const int tap = cc >> 1;
      const int f0 = (cc & 1) * 32 + 8 * (lane >> 4);
      const float wv = WV_task[c];
      short8 r;
      #pragma unroll
      for (int e = 0; e < 8; ++e)
        r[e] = bf16_bits(wv * Wc[((size_t)c * NF + f0 + e) * 9 + tap]);
      wfrag[ridx] = r;
    }
  }
}

// ---------------- kernel B: Qs (head-summed) + K -> bf16 hi/lo frag records, no LDS ----
// record (T, term): element (lane,e) = M[T*16 + (lane&15)][(term&1)*32 + 8*(lane>>4)+e]
// term = 2*(lo) + fhalf. wave w = fhalf; each thread emits hi+lo for q and k.
__global__ __launch_bounds__(128, 1) void qsk_kernel(
    const float* __restrict__ X, const float* __restrict__ WQ_task,
    const float* __restrict__ BQ_task, const float* __restrict__ WK_task,
    const float* __restrict__ BK_task, const float* __restrict__ WQ_t1,
    const float* __restrict__ WQ_x, const float* __restrict__ BQ,
    const float* __restrict__ WK_x, const float* __restrict__ BK,
    const float* __restrict__ prevQ,
    short8* __restrict__ qfrag, short8* __restrict__ kfrag)
{
  const int t = threadIdx.x;
  const int lane = t & 63;
  const int fh = t >> 6;                       // f-half, = wave
  const int h = lane >> 4;
  const int T = blockIdx.x;
  const int wh = T * 16 + (lane & 15);
  const int f0 = fh * 32 + 8 * h;

  // batch-issue all global loads into register arrays (72 in flight)
  float x[8];
  #pragma unroll
  for (int e = 0; e < 8; ++e) x[e] = X[(size_t)(f0 + e) * WH + wh];
  float pq[64];
  #pragma unroll
  for (int a = 0; a < NH; ++a)
    #pragma unroll
    for (int e = 0; e < 8; ++e)
      pq[a * 8 + e] = prevQ[(size_t)(a * 64 + f0 + e) * WH + wh];

  float wkx[8], bk[8], wkt[8], bkt[8], wqx[8];
  *(float4*)&wkx[0] = *(const float4*)&WK_x[f0];
  *(float4*)&wkx[4] = *(const float4*)&WK_x[f0 + 4];
  *(float4*)&bk[0]  = *(const float4*)&BK[f0];
  *(float4*)&bk[4]  = *(const float4*)&BK[f0 + 4];
  *(float4*)&wkt[0] = *(const float4*)&WK_task[f0];
  *(float4*)&wkt[4] = *(const float4*)&WK_task[f0 + 4];
  *(float4*)&bkt[0] = *(const float4*)&BK_task[f0];
  *(float4*)&bkt[4] = *(const float4*)&BK_task[f0 + 4];
  *(float4*)&wqx[0] = *(const float4*)&WQ_x[f0];
  *(float4*)&wqx[4] = *(const float4*)&WQ_x[f0 + 4];

  float q[8], k[8], xq[8];
  #pragma unroll
  for (int e = 0; e < 8; ++e) {
    k[e] = fmaf(wkt[e], fmaxf(fmaf(wkx[e], x[e], bk[e]), 0.f), bkt[e]);
    xq[e] = wqx[e] * x[e];
    q[e] = 0.f;
  }
  #pragma unroll
  for (int a = 0; a < NH; ++a) {
    const int af0 = a * 64 + f0;
    float w1[8], bq[8], wqt[8], bqt[8];
    *(float4*)&w1[0]  = *(const float4*)&WQ_t1[af0];
    *(float4*)&w1[4]  = *(const float4*)&WQ_t1[af0 + 4];
    *(float4*)&bq[0]  = *(const float4*)&BQ[af0];
    *(float4*)&bq[4]  = *(const float4*)&BQ[af0 + 4];
    *(float4*)&wqt[0] = *(const float4*)&WQ_task[af0];
    *(float4*)&wqt[4] = *(const float4*)&WQ_task[af0 + 4];
    *(float4*)&bqt[0] = *(const float4*)&BQ_task[af0];
    *(float4*)&bqt[4] = *(const float4*)&BQ_task[af0 + 4];
    #pragma unroll
    for (int e = 0; e < 8; ++e) {
      const float r = fmaxf(fmaf(w1[e], pq[a * 8 + e], xq[e] + bq[e]), 0.f);
      q[e] = fmaf(wqt[e], r, q[e]) + bqt[e];
    }
  }

  short8 qh, ql, kh, klo;
  #pragma unroll
  for (int e = 0; e < 8; ++e) {
    qh[e] = bf16_bits(q[e]);
    ql[e] = bf16_bits(q[e] - bf16_round(q[e]));
    kh[e] = bf16_bits(k[e]);
    klo[e] = bf16_bits(k[e] - bf16_round(k[e]));
  }
  qfrag[((size_t)T * 4 + fh) * 64 + lane] = qh;
  qfrag[((size_t)T * 4 + 2 + fh) * 64 + lane] = ql;
  kfrag[((size_t)T * 4 + fh) * 64 + lane] = kh;
  kfrag[((size_t)T * 4 + 2 + fh) * 64 + lane] = klo;
}

// ---------------- kernel C: conv via MFMA (K=576 im2col), K-dim split across wave pairs ----
// block: 256 thr = 4 waves; wave w: key-tile (b*2 + (w>>1)), K-half (w&1).
__global__ __launch_bounds__(256, 1) void vconv_kernel(
    const unsigned short* __restrict__ padX, const short8* __restrict__ wfrag,
    const float* __restrict__ bc, const float* __restrict__ WV_task,
    const float* __restrict__ BV_task, short8* __restrict__ vfrag)
{
  __shared__ float Vt[2][32][36];
  const int t = threadIdx.x;
  const int lane = t & 63, w = t >> 6;
  const int h = lane >> 4;
  const int b = blockIdx.x;
  const int ktloc = w >> 1, half = w & 1;
  const int key = (b * 2 + ktloc) * 16 + (lane & 15);
  const int kw = key / IMGH, kh = key - kw * IMGH;

  f32x4 acc0 = {0.f, 0.f, 0.f, 0.f}, acc1 = {0.f, 0.f, 0.f, 0.f};
  #pragma unroll
  for (int i = 0; i < 9; ++i) {
    const int cc = half * 9 + i;
    const int tap = cc >> 1;
    const int di = tap / 3, dj = tap - di * 3;
    const int f0 = (cc & 1) * 32 + 8 * h;
    const int sp = (kw + di) * PW + (kh + dj);
    short8 xf;
    #pragma unroll
    for (int e = 0; e < 8; ++e)
      xf[e] = (short)padX[(size_t)(f0 + e) * PPLANE + sp];
    const short8 wf0 = wfrag[(size_t)cc * 64 + lane];
    const short8 wf1 = wfrag[(size_t)(18 + cc) * 64 + lane];
    acc0 = __builtin_amdgcn_mfma_f32_16x16x32_bf16(wf0, xf, acc0, 0, 0, 0);
    acc1 = __builtin_amdgcn_mfma_f32_16x16x32_bf16(wf1, xf, acc1, 0, 0, 0);
  }
  // D layout: col = lane&15 (key), row = 4h+reg (c)
  const int klc = ktloc * 16 + (lane & 15);
  #pragma unroll
  for (int reg = 0; reg < 4; ++reg) {
    Vt[half][4 * h + reg][klc] = acc0[reg];
    Vt[half][16 + 4 * h + reg][klc] = acc1[reg];
  }
  __syncthreads();
  if (t < 128) {
    const int ct = t >> 6;
    const int c = ct * 16 + (lane & 15);
    const float bias = fmaf(WV_task[c], bc[c], BV_task[c]);
    short8 r;
    #pragma unroll
    for (int e = 0; e < 8; ++e) {
      const int kl2 = 16 * (e >> 2) + 4 * h + (e & 3);   // baked pi-permutation
      r[e] = bf16_bits(Vt[0][c][kl2] + Vt[1][c][kl2] + bias);
    }
    vfrag[((size_t)b * 2 + ct) * 64 + lane] = r;
  }
}

// ---------------- kernel D: MFMA flash attention (unchanged from round 2) ----------------
__global__ __launch_bounds__(256, 3) void flash_mfma(
    const short8* __restrict__ qfrag, const short8* __restrict__ kfrag,
    const short8* __restrict__ vfrag, float* __restrict__ part, int cps)
{
  const int t = threadIdx.x;
  const int lane = t & 63, wave = t >> 6;
  const int h = lane >> 4;
  const int qb = blockIdx.x;
  const int s = blockIdx.y;

  short8 qf[3][4];
  #pragma unroll
  for (int g = 0; g < 3; ++g)
    #pragma unroll
    for (int tm = 0; tm < 4; ++tm)
      qf[g][tm] = qfrag[((size_t)(qb * 3 + g) * 4 + tm) * 64 + lane];

  f32x4 acc[2][3];
  #pragma unroll
  for (int ct = 0; ct < 2; ++ct)
    #pragma unroll
    for (int g = 0; g < 3; ++g)
      acc[ct][g] = (f32x4){0.f, 0.f, 0.f, 0.f};
  float m[3] = {-1e30f, -1e30f, -1e30f};
  float l[3] = {0.f, 0.f, 0.f};

  const int cpw = cps >> 2;
  const int ch0 = s * cps + wave;
  for (int it = 0; it < cpw; ++it) {
    const int ch = ch0 + it * 4;
    short8 kf[2][4];
    #pragma unroll
    for (int kt = 0; kt < 2; ++kt)
      #pragma unroll
      for (int tm = 0; tm < 4; ++tm)
        kf[kt][tm] = kfrag[((size_t)(2 * ch + kt) * 4 + tm) * 64 + lane];
    short8 vf0 = vfrag[(size_t)(ch * 2 + 0) * 64 + lane];
    short8 vf1 = vfrag[(size_t)(ch * 2 + 1) * 64 + lane];

    f32x4 st[2][3];
    #pragma unroll
    for (int kt = 0; kt < 2; ++kt)
      #pragma unroll
      for (int g = 0; g < 3; ++g) {
        f32x4 a = (f32x4){0.f, 0.f, 0.f, 0.f};
        a = __builtin_amdgcn_mfma_f32_16x16x32_bf16(kf[kt][0], qf[g][0], a, 0, 0, 0);
        a = __builtin_amdgcn_mfma_f32_16x16x32_bf16(kf[kt][1], qf[g][1], a, 0, 0, 0);
        a = __builtin_amdgcn_mfma_f32_16x16x32_bf16(kf[kt][2], qf[g][0], a, 0, 0, 0);
        a = __builtin_amdgcn_mfma_f32_16x16x32_bf16(kf[kt][3], qf[g][1], a, 0, 0, 0);
        a = __builtin_amdgcn_mfma_f32_16x16x32_bf16(kf[kt][0], qf[g][2], a, 0, 0, 0);
        a = __builtin_amdgcn_mfma_f32_16x16x32_bf16(kf[kt][1], qf[g][3], a, 0, 0, 0);
        st[kt][g] = a;
      }

    #pragma unroll
    for (int g = 0; g < 3; ++g) {
      float p[8];
      #pragma unroll
      for (int e = 0; e < 4; ++e) { p[e] = st[0][g][e]; p[4 + e] = st[1][g][e]; }
      float tmax = fmaxf(fmaxf(fmaxf(p[0], p[1]), fmaxf(p[2], p[3])),
                         fmaxf(fmaxf(p[4], p[5]), fmaxf(p[6], p[7])));
      tmax = fmaxf(tmax, __shfl_xor(tmax, 16));
      tmax = fmaxf(tmax, __shfl_xor(tmax, 32));
      if (__any(tmax > m[g] + 8.f)) {
        const float nm = fmaxf(m[g], tmax);
        const float r = __expf(m[g] - nm);
        l[g] *= r;
        acc[0][g] *= r;
        acc[1][g] *= r;
        m[g] = nm;
      }
      short8 pb;
      float ls = 0.f;
      #pragma unroll
      for (int e = 0; e < 8; ++e) {
        const float pe = __expf(p[e] - m[g]);
        ls += pe;
        pb[e] = bf16_bits(pe);
      }
      l[g] += ls;
      acc[0][g] = __builtin_amdgcn_mfma_f32_16x16x32_bf16(vf0, pb, acc[0][g], 0, 0, 0);
      acc[1][g] = __builtin_amdgcn_mfma_f32_16x16x32_bf16(vf1, pb, acc[1][g], 0, 0, 0);
    }
  }

  const int u = s * 4 + wave;
  #pragma unroll
  for (int g = 0; g < 3; ++g) {
    float lf = l[g] + __shfl_xor(l[g], 16);
    lf += __shfl_xor(lf, 32);
    const int q = qb * 48 + g * 16 + (lane & 15);
    float* base = part + ((size_t)u * WH + q) * 36;
    *(f32x4*)(base + 0 + 4 * h) = acc[0][g];
    *(f32x4*)(base + 16 + 4 * h) = acc[1][g];
    if (h == 0) { base[32] = m[g]; base[33] = lf; }
  }
}

// ---------------- kernel E: merge partials -> out (C, W, H) ----------------
__global__ __launch_bounds__(256) void merge_kernel(
    const float* __restrict__ part, float* __restrict__ out, int units)
{
  const int t = threadIdx.x;
  const int cl = t & 31;
  const int wh = blockIdx.x * 8 + (t >> 5);
  float M = -1e30f;
  for (int u = 0; u < units; ++u)
    M = fmaxf(M, part[((size_t)u * WH + wh) * 36 + 32]);
  float L = 0.f, A = 0.f;
  for (int u = 0; u < units; ++u) {
    const float* base = part + ((size_t)u * WH + wh) * 36;
    const float e = __expf(base[32] - M);
    L = fmaf(e, base[33], L);
    A = fmaf(e, base[cl], A);
  }
  out[(size_t)cl * WH + wh] = A / L;
}

extern "C" void kernel_launch(void* const* d_in, const int* in_sizes, int n_in,
                              void* d_out, int out_size, void* d_ws, size_t ws_size,
                              hipStream_t stream)
{
  const float* X   = (const float*)d_in[0];
  const float* WQt = (const float*)d_in[1];
  const float* BQt = (const float*)d_in[2];
  const float* WKt = (const float*)d_in[3];
  const float* BKt = (const float*)d_in[4];
  const float* WVt = (const float*)d_in[5];
  const float* BVt = (const float*)d_in[6];
  const float* WQ1 = (const float*)d_in[7];
  const float* WQx = (const float*)d_in[8];
  const float* BQ  = (const float*)d_in[9];
  const float* WKx = (const float*)d_in[10];
  const float* BK  = (const float*)d_in[11];
  const float* Wc  = (const float*)d_in[12];
  const float* bc  = (const float*)d_in[13];
  const float* pQ  = (const float*)d_in[14];
  float* out = (float*)d_out;

  short8* qfrag = (short8*)d_ws;                      // 576*4*64 = 147456 recs
  short8* kfrag = qfrag + (size_t)147456;
  short8* vfrag = kfrag + (size_t)147456;             // 288*2*64 = 36864 recs
  short8* wfrag = vfrag + (size_t)36864;              // 2304 recs
  unsigned short* padX = (unsigned short*)(wfrag + 2304);   // 64*9604 ushorts
  float* part = (float*)((char*)padX + (size_t)614656 * 2);
  const size_t base_bytes = ((size_t)147456 * 2 + 36864 + 2304) * 16 + (size_t)614656 * 2;

  int ksplit = 4;
  while (ksplit > 1 &&
         base_bytes + (size_t)(4 * ksplit) * WH * 36 * sizeof(float) > ws_size)
    ksplit >>= 1;
  const int cps = 288 / ksplit;
  const int units = 4 * ksplit;

  pad_wpack_kernel<<<dim3(2402), 256, 0, stream>>>(X, Wc, WVt, padX, wfrag);
  qsk_kernel<<<dim3(576), 128, 0, stream>>>(X, WQt, BQt, WKt, BKt,
                                            WQ1, WQx, BQ, WKx, BK, pQ,
                                            qfrag, kfrag);
  vconv_kernel<<<dim3(288), 256, 0, stream>>>(padX, wfrag, bc, WVt, BVt, vfrag);
  flash_mfma<<<dim3(192, ksplit), 256, 0, stream>>>(qfrag, kfrag, vfrag, part, cps);
  merge_kernel<<<dim3(WH / 8), 256, 0, stream>>>(part, out, units);
}